// Round 13
// baseline (148.506 us; speedup 1.0000x reference)
//
#include <hip/hip_runtime.h>
#include <hip/hip_bf16.h>

#define N_NODES 50000
#define DIM 64
#define N_EDGES 800000
#define CAP 64          // padded-CSR capacity; P(deg>64) for Poisson(16) ~ e^-125
#define NTHR 256
#define GB_ROWS 32      // y-GEMM rows per block
#define NGB 1563        // ceil(50000/32)
#define NPB (N_EDGES / NTHR)            // 3125 place blocks
#define TOTAL_BLOCKS (NGB + NPB)        // 4688; b%3==0 -> gemm, else place

// ws layout: count[N_NODES] ints @0; yb = bf16 y[N_NODES*DIM] @256KB.
// csr[N_NODES*CAP] ints aliases d_out.

static __device__ inline unsigned int f2bf(float f) {
    __hip_bfloat16 h = __float2bfloat16(f);           // RNE
    return (unsigned int)*reinterpret_cast<unsigned short*>(&h);
}
static __device__ inline float bf_lo(unsigned int u) { return __uint_as_float(u << 16); }
static __device__ inline float bf_hi(unsigned int u) { return __uint_as_float(u & 0xffff0000u); }

// K1 (fused, interleaved block-specialization):
//   b%3==0 -> y = x @ W^T -> bf16 (32 rows/block); else -> place 1 edge/thread.
// GEMM branch: x read via wave-uniform global loads (scalarizable, 0 DS ops)
// and Wb spread-b128 from LDS (8/row). Only 8.2 KB LDS -> more co-resident
// zero-LDS place blocks; GEMM work fills their atomic-stall cycles.
__global__ __launch_bounds__(NTHR, 8) void place_gemm_kernel(
    const int* __restrict__ ei, const float* __restrict__ x,
    const float* __restrict__ W, int* __restrict__ count,
    int* csr, unsigned short* __restrict__ yb)
{
    __shared__ uint4 Wb[512];               // 8 KB bf16 quad-major W

    int t = threadIdx.x;
    int b = blockIdx.x;

    if (b % 3 == 0) {
        // ---- y-GEMM side (g = 0..1562) ----
        for (int m = t; m < 512; m += NTHR) {         // stride-1 b128 LDS writes
            int o = m & 63, j8 = m >> 6;
            const float* wr = W + o * DIM + j8 * 8;
            uint4 uw;
            uw.x = f2bf(wr[0]) | (f2bf(wr[1]) << 16);
            uw.y = f2bf(wr[2]) | (f2bf(wr[3]) << 16);
            uw.z = f2bf(wr[4]) | (f2bf(wr[5]) << 16);
            uw.w = f2bf(wr[6]) | (f2bf(wr[7]) << 16);
            Wb[m] = uw;
        }
        __syncthreads();

        int g  = b / 3;
        int R0 = g * GB_ROWS;
        int w  = t >> 6, l = t & 63;
        const float4* x4 = (const float4*)x;
#pragma unroll
        for (int i = 0; i < 8; i++) {
            int r = R0 + w * 8 + i;                   // wave-uniform row
            if (r < N_NODES) {
                const float4* xr = x4 + (size_t)r * 16;
                float acc = 0.f;
#pragma unroll
                for (int j8 = 0; j8 < 8; j8++) {
                    float4 x0 = xr[2 * j8];           // wave-uniform -> s_load
                    float4 x1 = xr[2 * j8 + 1];
                    uint4  wq = Wb[j8 * 64 + l];      // spread b128, conflict-free
                    acc += x0.x * bf_lo(wq.x) + x0.y * bf_hi(wq.x)
                         + x0.z * bf_lo(wq.y) + x0.w * bf_hi(wq.y)
                         + x1.x * bf_lo(wq.z) + x1.y * bf_hi(wq.z)
                         + x1.z * bf_lo(wq.w) + x1.w * bf_hi(wq.w);
                }
                yb[(size_t)r * DIM + l] = (unsigned short)f2bf(acc);  // 128B/wave
            }
        }
    } else {
        // ---- place side (p = 0..3124) ----
        int p = (b / 3) * 2 + (b % 3 - 1);
        int e = p * NTHR + t;                         // exact 800000
        int row = ei[e], col = ei[N_EDGES + e];
        int pos = atomicAdd(&count[row], 1);          // long pole, issued first
        if (pos < CAP) csr[row * CAP + pos] = col;    // dependent store last
    }
}

// K2: pure gather-mean over bf16 y + bias. 4 waves/block, 1 row/wave,
// 12500 blocks. No LDS, no barriers. 8 lanes/edge x uint4 (128B/edge).
// csr aliases out: all 64 lanes load the row's 256B csr chunk before the
// stores by lanes 0-7 overwrite the same region.
__global__ __launch_bounds__(NTHR) void agg_kernel(
    const unsigned short* __restrict__ yb, const int* __restrict__ count,
    const int* csr, const float* __restrict__ bias, float* out)
{
    int t   = threadIdx.x;
    int w   = t >> 6;
    int l   = t & 63;
    int sub = l & 7;                    // which 16B (8 feats) of the 128B row
    int grp = l >> 3;                   // edge group 0..7
    int r   = blockIdx.x * 4 + w;       // grid exact

    int deg = count[r];
    int dc  = deg < CAP ? deg : CAP;
    int myc = csr[(size_t)r * CAP + l];

    const uint4* ybq = (const uint4*)yb;
    float s[8];
#pragma unroll
    for (int q = 0; q < 8; q++) s[q] = 0.f;

    for (int jb = 0; jb < dc; jb += 8) {
        int  j     = jb + grp;
        int  c     = __shfl(myc, j);    // 1 bpermute per 8 edges
        bool valid = j < dc;
        int  cs    = valid ? c : 0;
        uint4 v = ybq[(size_t)cs * 8 + sub];
        if (valid) {
            s[0] += bf_lo(v.x); s[1] += bf_hi(v.x);
            s[2] += bf_lo(v.y); s[3] += bf_hi(v.y);
            s[4] += bf_lo(v.z); s[5] += bf_hi(v.z);
            s[6] += bf_lo(v.w); s[7] += bf_hi(v.w);
        }
    }
#pragma unroll
    for (int q = 0; q < 8; q++) {       // fold edge groups (lane bits 3..5)
        s[q] += __shfl_xor(s[q], 8);
        s[q] += __shfl_xor(s[q], 16);
        s[q] += __shfl_xor(s[q], 32);
    }

    if (grp == 0) {                     // lanes 0-7 write the full 256B row
        float inv_d = 1.0f / ((float)deg + 1e-6f);
        float4 b0 = ((const float4*)bias)[2 * sub];
        float4 b1 = ((const float4*)bias)[2 * sub + 1];
        float4 o0 = make_float4(s[0] * inv_d + b0.x, s[1] * inv_d + b0.y,
                                s[2] * inv_d + b0.z, s[3] * inv_d + b0.w);
        float4 o1 = make_float4(s[4] * inv_d + b1.x, s[5] * inv_d + b1.y,
                                s[6] * inv_d + b1.z, s[7] * inv_d + b1.w);
        ((float4*)(out + (size_t)r * DIM))[2 * sub]     = o0;
        ((float4*)(out + (size_t)r * DIM))[2 * sub + 1] = o1;
    }
}

extern "C" void kernel_launch(void* const* d_in, const int* in_sizes, int n_in,
                              void* d_out, int out_size, void* d_ws, size_t ws_size,
                              hipStream_t stream) {
    const float* x    = (const float*)d_in[0];
    const int*   ei   = (const int*)d_in[1];
    const float* W    = (const float*)d_in[2];
    const float* bias = (const float*)d_in[3];
    float* out = (float*)d_out;

    int*            count = (int*)d_ws;                                // 200 KB
    unsigned short* yb    = (unsigned short*)((char*)d_ws + 262144);   // 6.4 MB
    int*            csr   = (int*)d_out;                               // aliased

    hipMemsetAsync(count, 0, N_NODES * sizeof(int), stream);           // capture-legal
    place_gemm_kernel<<<TOTAL_BLOCKS, NTHR, 0, stream>>>(ei, x, W, count, csr, yb);
    agg_kernel<<<N_NODES / 4, NTHR, 0, stream>>>(yb, count, csr, bias, out);
}

// Round 14
// 132.429 us; speedup vs baseline: 1.1214x; 1.1214x over previous
//
#include <hip/hip_runtime.h>
#include <hip/hip_bf16.h>

#define N_NODES 50000
#define DIM 64
#define N_EDGES 800000
#define CAP 64          // padded-CSR capacity; P(deg>64) for Poisson(16) ~ e^-125
#define NTHR 256
#define GB_ROWS 32      // y-GEMM rows per block
#define SLICE 6250      // N_NODES / 8 rows per XCD slice
#define NGROUP 196      // 24-block groups: 8 GEMM + 16 place (2 chunks x 8 slices)
#define TOTAL_BLOCKS (NGROUP * 24)      // 4704
#define CHUNK_EDGES 2048                // per place-chunk; 392 chunks cover 800k

// ws layout: count[N_NODES] ints @0; yb = bf16 y[N_NODES*DIM] @256KB.
// csr[N_NODES*CAP] ints aliases d_out.

static __device__ inline unsigned int f2bf(float f) {
    __hip_bfloat16 h = __float2bfloat16(f);           // RNE
    return (unsigned int)*reinterpret_cast<unsigned short*>(&h);
}
static __device__ inline float bf_lo(unsigned int u) { return __uint_as_float(u << 16); }
static __device__ inline float bf_hi(unsigned int u) { return __uint_as_float(u & 0xffff0000u); }

// K1 (fused, interleaved block-specialization, XCD-partitioned place):
//   b%24 <  8 -> y = x @ W^T -> bf16 (32 rows/block)   [R12-proven form]
//   b%24 >= 8 -> place: scan a 2048-edge chunk, keep rows in slice b%8.
// Slice s==b%8 -> all atomics/csr-writes for slice s issue from XCD s
// (round-robin heuristic): count stays in one L2, csr lines fill fully
// before write-back (kills the 16x partial-line write amplification).
__global__ __launch_bounds__(NTHR, 8) void place_gemm_kernel(
    const int* __restrict__ ei, const float* __restrict__ x,
    const float* __restrict__ W, int* __restrict__ count,
    int* csr, unsigned short* __restrict__ yb)
{
    __shared__ uint4  Wb[512];              // 8 KB bf16 quad-major W
    __shared__ float4 xs4[GB_ROWS * 16];    // 8 KB fp32 x rows

    int t = threadIdx.x;
    int b = blockIdx.x;
    int m = b % 24;

    if (m < 8) {
        // ---- y-GEMM side: g = (b/24)*8 + m in [0, 1568) ----
        int g  = (b / 24) * 8 + m;
        int R0 = g * GB_ROWS;
        const float4* x4 = (const float4*)x;
        for (int i = t; i < GB_ROWS * 16; i += NTHR) {
            int q = R0 * 16 + i;
            xs4[i] = (q < N_NODES * 16) ? x4[q] : make_float4(0.f, 0.f, 0.f, 0.f);
        }
        for (int k = t; k < 512; k += NTHR) {         // stride-1 b128 LDS writes
            int o = k & 63, j8 = k >> 6;
            const float* wr = W + o * DIM + j8 * 8;
            uint4 uw;
            uw.x = f2bf(wr[0]) | (f2bf(wr[1]) << 16);
            uw.y = f2bf(wr[2]) | (f2bf(wr[3]) << 16);
            uw.z = f2bf(wr[4]) | (f2bf(wr[5]) << 16);
            uw.w = f2bf(wr[6]) | (f2bf(wr[7]) << 16);
            Wb[k] = uw;
        }
        __syncthreads();

        int w = t >> 6, l = t & 63;
#pragma unroll
        for (int i = 0; i < 8; i++) {
            int rl = w * 8 + i;                       // wave-uniform local row
            int r  = R0 + rl;
            if (r < N_NODES) {
                float acc = 0.f;
#pragma unroll
                for (int j8 = 0; j8 < 8; j8++) {
                    uint4  wq = Wb[j8 * 64 + l];      // spread b128, conflict-free
                    float4 x0 = xs4[rl * 16 + 2 * j8];     // broadcast b128
                    float4 x1 = xs4[rl * 16 + 2 * j8 + 1];
                    acc += x0.x * bf_lo(wq.x) + x0.y * bf_hi(wq.x)
                         + x0.z * bf_lo(wq.y) + x0.w * bf_hi(wq.y)
                         + x1.x * bf_lo(wq.z) + x1.y * bf_hi(wq.z)
                         + x1.z * bf_lo(wq.w) + x1.w * bf_hi(wq.w);
                }
                yb[(size_t)r * DIM + l] = (unsigned short)f2bf(acc);  // 128B/wave
            }
        }
    } else {
        // ---- place side: slice s = b%8 (== (m-8)%8), chunk q ----
        int s    = b & 7;
        int q    = (b / 24) * 2 + ((m - 8) >> 3);     // 0..391
        int base = q * CHUNK_EDGES;
#pragma unroll
        for (int k = 0; k < CHUNK_EDGES / NTHR; k++) {
            int e = base + k * NTHR + t;
            if (e < N_EDGES) {
                int row = ei[e];                      // streamed, L2/L3-warm
                if (row / SLICE == s) {               // keep ~1/8 of edges
                    int col = ei[N_EDGES + e];
                    int pos = atomicAdd(&count[row], 1);   // XCD-local L2
                    if (pos < CAP) csr[row * CAP + pos] = col;
                }
            }
        }
    }
}

// K2: pure gather-mean over bf16 y + bias. 1 row/wave, slice-mapped so each
// block's csr reads / count reads / out writes hit its own XCD's L2.
// csr aliases out: all 64 lanes load the row's 256B csr chunk before the
// stores by lanes 0-7 overwrite the same region.
__global__ __launch_bounds__(NTHR) void agg_kernel(
    const unsigned short* __restrict__ yb, const int* __restrict__ count,
    const int* csr, const float* __restrict__ bias, float* out)
{
    int t   = threadIdx.x;
    int w   = t >> 6;
    int l   = t & 63;
    int sub = l & 7;                    // which 16B (8 feats) of the 128B row
    int grp = l >> 3;                   // edge group 0..7
    int sb  = blockIdx.x & 7;           // row slice (== XCD, heuristically)
    int i   = blockIdx.x >> 3;          // 0..1562
    int rl  = i * 4 + w;
    if (rl >= SLICE) return;            // tail guard (last block per slice)
    int r = sb * SLICE + rl;

    int deg = count[r];
    int dc  = deg < CAP ? deg : CAP;
    int myc = csr[(size_t)r * CAP + l];

    const uint4* ybq = (const uint4*)yb;
    float s[8];
#pragma unroll
    for (int q = 0; q < 8; q++) s[q] = 0.f;

    for (int jb = 0; jb < dc; jb += 8) {
        int  j     = jb + grp;
        int  c     = __shfl(myc, j);    // 1 bpermute per 8 edges
        bool valid = j < dc;
        int  cs    = valid ? c : 0;
        uint4 v = ybq[(size_t)cs * 8 + sub];
        if (valid) {
            s[0] += bf_lo(v.x); s[1] += bf_hi(v.x);
            s[2] += bf_lo(v.y); s[3] += bf_hi(v.y);
            s[4] += bf_lo(v.z); s[5] += bf_hi(v.z);
            s[6] += bf_lo(v.w); s[7] += bf_hi(v.w);
        }
    }
#pragma unroll
    for (int q = 0; q < 8; q++) {       // fold edge groups (lane bits 3..5)
        s[q] += __shfl_xor(s[q], 8);
        s[q] += __shfl_xor(s[q], 16);
        s[q] += __shfl_xor(s[q], 32);
    }

    if (grp == 0) {                     // lanes 0-7 write the full 256B row
        float inv_d = 1.0f / ((float)deg + 1e-6f);
        float4 b0 = ((const float4*)bias)[2 * sub];
        float4 b1 = ((const float4*)bias)[2 * sub + 1];
        float4 o0 = make_float4(s[0] * inv_d + b0.x, s[1] * inv_d + b0.y,
                                s[2] * inv_d + b0.z, s[3] * inv_d + b0.w);
        float4 o1 = make_float4(s[4] * inv_d + b1.x, s[5] * inv_d + b1.y,
                                s[6] * inv_d + b1.z, s[7] * inv_d + b1.w);
        ((float4*)(out + (size_t)r * DIM))[2 * sub]     = o0;
        ((float4*)(out + (size_t)r * DIM))[2 * sub + 1] = o1;
    }
}

extern "C" void kernel_launch(void* const* d_in, const int* in_sizes, int n_in,
                              void* d_out, int out_size, void* d_ws, size_t ws_size,
                              hipStream_t stream) {
    const float* x    = (const float*)d_in[0];
    const int*   ei   = (const int*)d_in[1];
    const float* W    = (const float*)d_in[2];
    const float* bias = (const float*)d_in[3];
    float* out = (float*)d_out;

    int*            count = (int*)d_ws;                                // 200 KB
    unsigned short* yb    = (unsigned short*)((char*)d_ws + 262144);   // 6.4 MB
    int*            csr   = (int*)d_out;                               // aliased

    hipMemsetAsync(count, 0, N_NODES * sizeof(int), stream);           // capture-legal
    place_gemm_kernel<<<TOTAL_BLOCKS, NTHR, 0, stream>>>(ei, x, W, count, csr, yb);
    agg_kernel<<<8 * ((SLICE + 3) / 4 + ((SLICE % 4) ? 0 : 0)), NTHR, 0, stream>>>(yb, count, csr, bias, out);
}

// Round 15
// 129.609 us; speedup vs baseline: 1.1458x; 1.0218x over previous
//
#include <hip/hip_runtime.h>
#include <hip/hip_bf16.h>

#define N_NODES 50000
#define DIM 64
#define N_EDGES 800000
#define CAP 64          // padded-CSR capacity; P(deg>64) for Poisson(16) ~ e^-125
#define NTHR 256
#define GB_ROWS 32      // y-GEMM rows per block
#define SLICE 6250      // N_NODES / 8 rows per XCD slice
#define NGROUP 196      // 24-block groups: 8 GEMM + 16 place (2 chunks x 8 slices)
#define TOTAL_BLOCKS (NGROUP * 24)      // 4704
#define CHUNK_EDGES 2048                // per place-chunk; 392 chunks cover 800k

// ws layout: count[N_NODES] ints @0; yb = bf16 y[N_NODES*DIM] @256KB.
// csr[N_NODES*CAP] ints aliases d_out.

static __device__ inline unsigned int f2bf(float f) {
    __hip_bfloat16 h = __float2bfloat16(f);           // RNE
    return (unsigned int)*reinterpret_cast<unsigned short*>(&h);
}
static __device__ inline float bf_lo(unsigned int u) { return __uint_as_float(u << 16); }
static __device__ inline float bf_hi(unsigned int u) { return __uint_as_float(u & 0xffff0000u); }

// K1 (fused, interleaved block-specialization, XCD-partitioned place):
//   b%24 <  8 -> y = x @ W^T -> bf16 (32 rows/block)   [R12-proven form]
//   b%24 >= 8 -> place: scan a 2048-edge chunk (int4 row stream, 8 edges/
//                thread), keep rows in slice b%8 (sub+cmp, no divide).
// Slice s==b%8: all atomics/csr-writes for slice s issue from one XCD
// (round-robin heuristic) -> count stays in one L2, csr lines fill fully.
__global__ __launch_bounds__(NTHR, 8) void place_gemm_kernel(
    const int* __restrict__ ei, const float* __restrict__ x,
    const float* __restrict__ W, int* __restrict__ count,
    int* csr, unsigned short* __restrict__ yb)
{
    __shared__ uint4  Wb[512];              // 8 KB bf16 quad-major W
    __shared__ float4 xs4[GB_ROWS * 16];    // 8 KB fp32 x rows

    int t = threadIdx.x;
    int b = blockIdx.x;
    int m = b % 24;

    if (m < 8) {
        // ---- y-GEMM side: g = (b/24)*8 + m in [0, 1568) ----
        int g  = (b / 24) * 8 + m;
        int R0 = g * GB_ROWS;
        const float4* x4 = (const float4*)x;
        for (int i = t; i < GB_ROWS * 16; i += NTHR) {
            int q = R0 * 16 + i;
            xs4[i] = (q < N_NODES * 16) ? x4[q] : make_float4(0.f, 0.f, 0.f, 0.f);
        }
        for (int k = t; k < 512; k += NTHR) {         // stride-1 b128 LDS writes
            int o = k & 63, j8 = k >> 6;
            const float* wr = W + o * DIM + j8 * 8;
            uint4 uw;
            uw.x = f2bf(wr[0]) | (f2bf(wr[1]) << 16);
            uw.y = f2bf(wr[2]) | (f2bf(wr[3]) << 16);
            uw.z = f2bf(wr[4]) | (f2bf(wr[5]) << 16);
            uw.w = f2bf(wr[6]) | (f2bf(wr[7]) << 16);
            Wb[k] = uw;
        }
        __syncthreads();

        int w = t >> 6, l = t & 63;
#pragma unroll
        for (int i = 0; i < 8; i++) {
            int rl = w * 8 + i;                       // wave-uniform local row
            int r  = R0 + rl;
            if (r < N_NODES) {
                float acc = 0.f;
#pragma unroll
                for (int j8 = 0; j8 < 8; j8++) {
                    uint4  wq = Wb[j8 * 64 + l];      // spread b128, conflict-free
                    float4 x0 = xs4[rl * 16 + 2 * j8];     // broadcast b128
                    float4 x1 = xs4[rl * 16 + 2 * j8 + 1];
                    acc += x0.x * bf_lo(wq.x) + x0.y * bf_hi(wq.x)
                         + x0.z * bf_lo(wq.y) + x0.w * bf_hi(wq.y)
                         + x1.x * bf_lo(wq.z) + x1.y * bf_hi(wq.z)
                         + x1.z * bf_lo(wq.w) + x1.w * bf_hi(wq.w);
                }
                yb[(size_t)r * DIM + l] = (unsigned short)f2bf(acc);  // 128B/wave
            }
        }
    } else {
        // ---- place side: slice s = b&7, chunk q; 8 edges/thread via int4 ----
        int s    = b & 7;
        int lo   = s * SLICE;
        int q    = (b / 24) * 2 + ((m - 8) >> 3);     // 0..391
        int e0   = q * CHUNK_EDGES + t * 8;           // 8-aligned; 800000%8==0
        if (e0 < N_EDGES) {                           // whole group in or out
            const int4* rp = (const int4*)(ei + e0);
            int4 ra = rp[0];
            int4 rb = rp[1];
            int rows[8] = {ra.x, ra.y, ra.z, ra.w, rb.x, rb.y, rb.z, rb.w};
#pragma unroll
            for (int k = 0; k < 8; k++) {
                if ((unsigned)(rows[k] - lo) < (unsigned)SLICE) {
                    int col = ei[N_EDGES + e0 + k];
                    int pos = atomicAdd(&count[rows[k]], 1);   // XCD-local L2
                    if (pos < CAP) csr[rows[k] * CAP + pos] = col;
                }
            }
        }
    }
}

// K2: pure gather-mean over bf16 y + bias. 1 row/wave, slice-mapped to keep
// csr/count/out traffic XCD-local. Gather is software-pipelined: batch N+1's
// load issues before batch N's unpack-adds consume the register.
// csr aliases out: all 64 lanes load the row's 256B csr chunk before the
// stores by lanes 0-7 overwrite the same region.
__global__ __launch_bounds__(NTHR) void agg_kernel(
    const unsigned short* __restrict__ yb, const int* __restrict__ count,
    const int* csr, const float* __restrict__ bias, float* out)
{
    int t   = threadIdx.x;
    int w   = t >> 6;
    int l   = t & 63;
    int sub = l & 7;                    // which 16B (8 feats) of the 128B row
    int grp = l >> 3;                   // edge group 0..7
    int sb  = blockIdx.x & 7;           // row slice (== XCD, heuristically)
    int i   = blockIdx.x >> 3;          // 0..1562
    int rl  = i * 4 + w;
    if (rl >= SLICE) return;            // tail guard
    int r = sb * SLICE + rl;

    int deg = count[r];
    int dc  = deg < CAP ? deg : CAP;
    int myc = csr[(size_t)r * CAP + l];

    const uint4* ybq = (const uint4*)yb;
    float s[8];
#pragma unroll
    for (int q = 0; q < 8; q++) s[q] = 0.f;

    // prefetch batch 0
    bool valid = grp < dc;
    {
        int c0 = __shfl(myc, grp);
        int cs = valid ? c0 : 0;
        uint4 v = ybq[(size_t)cs * 8 + sub];
        for (int jb = 8; jb < dc; jb += 8) {
            int  j2     = jb + grp;
            int  c2     = __shfl(myc, j2);
            bool valid2 = j2 < dc;
            int  cs2    = valid2 ? c2 : 0;
            uint4 v2 = ybq[(size_t)cs2 * 8 + sub];     // next batch in flight
            if (valid) {
                s[0] += bf_lo(v.x); s[1] += bf_hi(v.x);
                s[2] += bf_lo(v.y); s[3] += bf_hi(v.y);
                s[4] += bf_lo(v.z); s[5] += bf_hi(v.z);
                s[6] += bf_lo(v.w); s[7] += bf_hi(v.w);
            }
            v = v2; valid = valid2;
        }
        if (valid) {
            s[0] += bf_lo(v.x); s[1] += bf_hi(v.x);
            s[2] += bf_lo(v.y); s[3] += bf_hi(v.y);
            s[4] += bf_lo(v.z); s[5] += bf_hi(v.z);
            s[6] += bf_lo(v.w); s[7] += bf_hi(v.w);
        }
    }
#pragma unroll
    for (int q = 0; q < 8; q++) {       // fold edge groups (lane bits 3..5)
        s[q] += __shfl_xor(s[q], 8);
        s[q] += __shfl_xor(s[q], 16);
        s[q] += __shfl_xor(s[q], 32);
    }

    if (grp == 0) {                     // lanes 0-7 write the full 256B row
        float inv_d = 1.0f / ((float)deg + 1e-6f);
        float4 b0 = ((const float4*)bias)[2 * sub];
        float4 b1 = ((const float4*)bias)[2 * sub + 1];
        float4 o0 = make_float4(s[0] * inv_d + b0.x, s[1] * inv_d + b0.y,
                                s[2] * inv_d + b0.z, s[3] * inv_d + b0.w);
        float4 o1 = make_float4(s[4] * inv_d + b1.x, s[5] * inv_d + b1.y,
                                s[6] * inv_d + b1.z, s[7] * inv_d + b1.w);
        ((float4*)(out + (size_t)r * DIM))[2 * sub]     = o0;
        ((float4*)(out + (size_t)r * DIM))[2 * sub + 1] = o1;
    }
}

extern "C" void kernel_launch(void* const* d_in, const int* in_sizes, int n_in,
                              void* d_out, int out_size, void* d_ws, size_t ws_size,
                              hipStream_t stream) {
    const float* x    = (const float*)d_in[0];
    const int*   ei   = (const int*)d_in[1];
    const float* W    = (const float*)d_in[2];
    const float* bias = (const float*)d_in[3];
    float* out = (float*)d_out;

    int*            count = (int*)d_ws;                                // 200 KB
    unsigned short* yb    = (unsigned short*)((char*)d_ws + 262144);   // 6.4 MB
    int*            csr   = (int*)d_out;                               // aliased

    hipMemsetAsync(count, 0, N_NODES * sizeof(int), stream);           // capture-legal
    place_gemm_kernel<<<TOTAL_BLOCKS, NTHR, 0, stream>>>(ei, x, W, count, csr, yb);
    agg_kernel<<<8 * 1563, NTHR, 0, stream>>>(yb, count, csr, bias, out);
}